// Round 1
// baseline (306620.581 us; speedup 1.0000x reference)
//
#include <hip/hip_runtime.h>

// LSTM (H=64, IN=1) sequential scan, T=524288 steps, single block of 256
// threads on one CU. Thread (w = tid>>6, l = tid&63) owns gate-type (l&3)
// of hidden unit u = 16w + (l>>2), i.e. all four gates of a unit live in
// 4 adjacent lanes of ONE wave -> gate exchange is intra-wave (no barrier).
// Only one __syncthreads per step (the h broadcast, double-buffered).

__device__ __forceinline__ float fast_sig(float x) {
    // sigmoid(x) = 1/(1+e^-x); v_exp + v_rcp, ~1e-7 rel error
    return __builtin_amdgcn_rcpf(1.0f + __expf(-x));
}

__global__ __launch_bounds__(256, 1)
void lstm_seq_kernel(const float* __restrict__ seq,
                     const float* __restrict__ W_ih,
                     const float* __restrict__ W_hh,
                     const float* __restrict__ b_ih,
                     const float* __restrict__ b_hh,
                     const float* __restrict__ W_lin,
                     const float* __restrict__ b_lin,
                     float* __restrict__ out,
                     int T)
{
    __shared__ float h_buf[2][64];     // double-buffered hidden state
    __shared__ float act_buf[4][64];   // per-wave gate-activation exchange
    __shared__ float x_lds[2][256];    // double-buffered input chunks

    const int tid = threadIdx.x;
    const int w   = tid >> 6;          // wave 0..3
    const int l   = tid & 63;          // lane
    const int gt  = l & 3;             // gate type: 0=i 1=f 2=g(tanh) 3=o
    const int u   = (w << 4) + (l >> 2);  // hidden unit 0..63
    const int row = (gt << 6) + u;     // row in [4H] PyTorch gate order

    // W_hh row pinned in registers (64 VGPRs)
    float wrow[64];
#pragma unroll
    for (int k = 0; k < 64; k += 4) {
        float4 v = *reinterpret_cast<const float4*>(W_hh + row * 64 + k);
        wrow[k]   = v.x; wrow[k+1] = v.y;
        wrow[k+2] = v.z; wrow[k+3] = v.w;
    }
    const float wih  = W_ih[row];
    const float bias = b_ih[row] + b_hh[row];
    // branchless activation: a = osc * sigmoid(asc * g) + ooff
    const float asc  = (gt == 2) ? 2.0f : 1.0f;
    const float osc  = (gt == 2) ? 2.0f : 1.0f;
    const float ooff = (gt == 2) ? -1.0f : 0.0f;

    if (tid < 64) { h_buf[0][tid] = 0.0f; h_buf[1][tid] = 0.0f; }
    if (tid < T)  x_lds[0][tid] = seq[tid];   // chunk 0
    float c = 0.0f;
    __syncthreads();

    for (int t = 0; t < T; ++t) {
        const int tm = t & 255;
        const int cb = (t >> 8) & 1;
        if (tm == 0) {                       // prefetch next 256-step chunk
            const int idx = t + 256 + tid;
            if (idx < T) x_lds[cb ^ 1][tid] = seq[idx];
        }
        const float  xv = x_lds[cb][tm];     // broadcast read
        const float* hb = h_buf[t & 1];

        // gate preactivation: gx + dot(W_hh[row,:], h)  (4 accumulators)
        float a0 = fmaf(xv, wih, bias);
        float a1 = 0.0f, a2 = 0.0f, a3 = 0.0f;
#pragma unroll
        for (int k = 0; k < 64; k += 4) {
            float4 hv = *reinterpret_cast<const float4*>(hb + k);
            a0 = fmaf(wrow[k],   hv.x, a0);
            a1 = fmaf(wrow[k+1], hv.y, a1);
            a2 = fmaf(wrow[k+2], hv.z, a2);
            a3 = fmaf(wrow[k+3], hv.w, a3);
        }
        const float g = (a0 + a1) + (a2 + a3);

        // activation (sigmoid for i,f,o; tanh = 2*sig(2x)-1 for g)
        const float s = fast_sig(g * asc);
        const float a = fmaf(s, osc, ooff);

        // intra-wave exchange of the 4 gate values of unit u
        float* ab = act_buf[w];
        ab[l] = a;
        asm volatile("s_waitcnt lgkmcnt(0)" ::: "memory");
        const float4 g4 = *reinterpret_cast<const float4*>(ab + ((l >> 2) << 2));

        // cell update (replicated across the 4 lanes of the unit group)
        c = fmaf(g4.y, c, g4.x * g4.z);                 // c = f*c + i*g
        const float tc = 1.0f - 2.0f * __builtin_amdgcn_rcpf(1.0f + __expf(2.0f * c));
        const float hu = g4.w * tc;                      // h = o * tanh(c)
        if (gt == 0) h_buf[(t + 1) & 1][u] = hu;
        __syncthreads();                                 // h visible to all waves
    }

    // head: out = dot(W_lin, h_last) + b_lin
    if (tid < 64) {
        float v = h_buf[T & 1][tid] * W_lin[tid];
#pragma unroll
        for (int m = 32; m >= 1; m >>= 1) v += __shfl_xor(v, m, 64);
        if (tid == 0) out[0] = v + b_lin[0];
    }
}

extern "C" void kernel_launch(void* const* d_in, const int* in_sizes, int n_in,
                              void* d_out, int out_size, void* d_ws, size_t ws_size,
                              hipStream_t stream) {
    const float* seq   = (const float*)d_in[0];
    const float* W_ih  = (const float*)d_in[1];
    const float* W_hh  = (const float*)d_in[2];
    const float* b_ih  = (const float*)d_in[3];
    const float* b_hh  = (const float*)d_in[4];
    const float* W_lin = (const float*)d_in[5];
    const float* b_lin = (const float*)d_in[6];
    float* out = (float*)d_out;
    const int T = in_sizes[0];   // IN=1 -> flat length == T

    hipLaunchKernelGGL(lstm_seq_kernel, dim3(1), dim3(256), 0, stream,
                       seq, W_ih, W_hh, b_ih, b_hh, W_lin, b_lin, out, T);
}

// Round 3
// 254250.415 us; speedup vs baseline: 1.2060x; 1.2060x over previous
//
#include <hip/hip_runtime.h>

// LSTM (H=64, IN=1) sequential scan, T=524288, one block of 256 threads on
// one CU (4 waves). Thread (w=tid>>6, l=tid&63) owns gate-type gt=l&3 of
// hidden unit u=16w+(l>>2): all 4 gates of a unit live in one DPP quad, so
// the gate exchange is 3 quad_perm DPP moves + cndmask selects (no LDS, no
// waitcnt). One __syncthreads per step (cross-wave h broadcast, dbuf).
// W_hh row held in 16 NAMED float4 regs (round-1 VGPR=60 proved float[64]
// was not register-resident -> weights re-fetched every step).

template <int CTRL>
__device__ __forceinline__ float qperm(float x) {
    // quad_perm DPP; CTRL must be a compile-time constant (round-2 fix)
    return __int_as_float(
        __builtin_amdgcn_update_dpp(__float_as_int(x), __float_as_int(x),
                                    CTRL, 0xf, 0xf, false));
}

__global__ __launch_bounds__(256, 1)
void lstm_seq_kernel(const float* __restrict__ seq,
                     const float* __restrict__ W_ih,
                     const float* __restrict__ W_hh,
                     const float* __restrict__ b_ih,
                     const float* __restrict__ b_hh,
                     const float* __restrict__ W_lin,
                     const float* __restrict__ b_lin,
                     float* __restrict__ out,
                     int T)
{
    __shared__ float h_buf[2][64];     // double-buffered hidden state
    __shared__ float x_lds[2][256];    // double-buffered input chunks

    const int tid = threadIdx.x;
    const int w   = tid >> 6;
    const int l   = tid & 63;
    const int gt  = l & 3;                 // 0=i 1=f 2=g(tanh) 3=o
    const int u   = (w << 4) + (l >> 2);   // hidden unit 0..63
    const int row = (gt << 6) + u;         // row in [4H], PyTorch order

    // ---- W_hh row pinned in 16 named float4 registers ----
    const float4* wp = reinterpret_cast<const float4*>(W_hh + row * 64);
    const float4 w0 = wp[0],  w1 = wp[1],  w2 = wp[2],  w3 = wp[3];
    const float4 w4 = wp[4],  w5 = wp[5],  w6 = wp[6],  w7 = wp[7];
    const float4 w8 = wp[8],  w9 = wp[9],  wA = wp[10], wB = wp[11];
    const float4 wC = wp[12], wD = wp[13], wE = wp[14], wF = wp[15];

    const float wih  = W_ih[row];
    const float bias = b_ih[row] + b_hh[row];
    // branchless activation: a = osc * sigmoid(asc*g) + ooff (tanh for gt==2)
    const float asc  = (gt == 2) ? 2.0f : 1.0f;
    const float osc  = (gt == 2) ? 2.0f : 1.0f;
    const float ooff = (gt == 2) ? -1.0f : 0.0f;
    const bool  m1   = (gt & 1) != 0;      // loop-invariant select masks
    const bool  m2   = (gt & 2) != 0;
    const bool  wr_h = (gt == 0);

    if (tid < 64) { h_buf[0][tid] = 0.0f; h_buf[1][tid] = 0.0f; }
    x_lds[0][tid] = seq[tid];
    float c = 0.0f;
    __syncthreads();

    for (int t = 0; t < T; ++t) {
        const int tm = t & 255;
        const int cb = (t >> 8) & 1;
        if (tm == 0) {                      // prefetch next 256-step chunk
            const int idx = t + 256 + tid;
            if (idx < T) x_lds[cb ^ 1][tid] = seq[idx];
        }
        const float  xv  = x_lds[cb][tm];
        const float4* hb = reinterpret_cast<const float4*>(h_buf[t & 1]);

        // ---- gate preactivation: wih*x + bias + dot(Wrow, h) ----
        float a0 = fmaf(xv, wih, bias);
        float a1 = 0.0f, a2 = 0.0f, a3 = 0.0f;
#define MAC(W, J) { const float4 hv = hb[J];                 \
        a0 = fmaf(W.x, hv.x, a0); a1 = fmaf(W.y, hv.y, a1);  \
        a2 = fmaf(W.z, hv.z, a2); a3 = fmaf(W.w, hv.w, a3); }
        MAC(w0, 0)  MAC(w1, 1)  MAC(w2, 2)  MAC(w3, 3)
        MAC(w4, 4)  MAC(w5, 5)  MAC(w6, 6)  MAC(w7, 7)
        MAC(w8, 8)  MAC(w9, 9)  MAC(wA, 10) MAC(wB, 11)
        MAC(wC, 12) MAC(wD, 13) MAC(wE, 14) MAC(wF, 15)
#undef MAC
        const float g = (a0 + a1) + (a2 + a3);

        // activation (sigmoid for i,f,o; tanh = 2*sig(2x)-1 for g)
        const float s = __builtin_amdgcn_rcpf(1.0f + __expf(-(g * asc)));
        const float a = fmaf(s, osc, ooff);

        // ---- quad DPP exchange: lane gets gates {gt, gt^1, gt^2, gt^3} ----
        const float s1 = qperm<0xB1>(a);    // quad_perm [1,0,3,2] -> gt^1
        const float s2 = qperm<0x4E>(a);    // quad_perm [2,3,0,1] -> gt^2
        const float s3 = qperm<0x1B>(a);    // quad_perm [3,2,1,0] -> gt^3
        // i*g: even gt -> a*s2, odd gt -> s1*s3
        const float ig = m1 ? (s1 * s3) : (a * s2);
        // f (gate 1): gt=0->s1 1->a 2->s3 3->s2
        const float f  = m1 ? (m2 ? s2 : a) : (m2 ? s3 : s1);
        // o (gate 3): gt=0->s3 1->s2 2->s1 3->a
        const float o  = m1 ? (m2 ? a : s2) : (m2 ? s1 : s3);

        // ---- cell + hidden update (replicated across the quad) ----
        c = fmaf(f, c, ig);
        const float tc = 1.0f - 2.0f * __builtin_amdgcn_rcpf(1.0f + __expf(2.0f * c));
        const float hu = o * tc;
        if (wr_h) h_buf[(t + 1) & 1][u] = hu;
        __syncthreads();
    }

    // head: out = dot(W_lin, h_last) + b_lin
    if (tid < 64) {
        float v = h_buf[T & 1][tid] * W_lin[tid];
#pragma unroll
        for (int m = 32; m >= 1; m >>= 1) v += __shfl_xor(v, m, 64);
        if (tid == 0) out[0] = v + b_lin[0];
    }
}

extern "C" void kernel_launch(void* const* d_in, const int* in_sizes, int n_in,
                              void* d_out, int out_size, void* d_ws, size_t ws_size,
                              hipStream_t stream) {
    const float* seq   = (const float*)d_in[0];
    const float* W_ih  = (const float*)d_in[1];
    const float* W_hh  = (const float*)d_in[2];
    const float* b_ih  = (const float*)d_in[3];
    const float* b_hh  = (const float*)d_in[4];
    const float* W_lin = (const float*)d_in[5];
    const float* b_lin = (const float*)d_in[6];
    float* out = (float*)d_out;
    const int T = in_sizes[0];

    hipLaunchKernelGGL(lstm_seq_kernel, dim3(1), dim3(256), 0, stream,
                       seq, W_ih, W_hh, b_ih, b_hh, W_lin, b_lin, out, T);
}